// Round 1
// baseline (395.704 us; speedup 1.0000x reference)
//
#include <hip/hip_runtime.h>

typedef __attribute__((ext_vector_type(4))) float f32x4;
typedef __attribute__((ext_vector_type(8))) short bf16x8;

#define MFMA16(a, b, c) __builtin_amdgcn_mfma_f32_16x16x32_bf16((a), (b), (c), 0, 0, 0)
#define LOG2E 1.44269504088896340736f

static __device__ __forceinline__ float bf2f(short u) {
  unsigned x = ((unsigned)(unsigned short)u) << 16;
  return __builtin_bit_cast(float, x);
}
static __device__ __forceinline__ short f2bf(float f) {
  unsigned u = __builtin_bit_cast(unsigned, f);
  u += 0x7fffu + ((u >> 16) & 1u);
  return (short)(u >> 16);
}
// global -> LDS direct DMA, 16B per lane. LDS dest must be wave-uniform base;
// HW writes lane i at base + i*16 (guide §5). Swizzling is done on the GLOBAL
// source address (rule #21 / m173): LDS stays linear.
static __device__ __forceinline__ void gll16(const void* g, void* l) {
  __builtin_amdgcn_global_load_lds(
      (const __attribute__((address_space(1))) unsigned*)(unsigned long long)g,
      (__attribute__((address_space(3))) unsigned*)(unsigned)(unsigned long long)l,
      16, 0, 0);
}

// ---------------- f32 -> bf16 conversion (vectorized, G13) ----------------
__global__ void __launch_bounds__(256) cvt_kernel(const float* __restrict__ src,
                                                  short* __restrict__ dst,
                                                  long long n) {
  long long i = ((long long)blockIdx.x * 256 + threadIdx.x) * 8;
  const long long stride = (long long)gridDim.x * 256 * 8;
  for (; i < n; i += stride) {
    f32x4 a = *(const f32x4*)(src + i);
    f32x4 b = *(const f32x4*)(src + i + 4);
    bf16x8 o;
    o[0] = f2bf(a[0]); o[1] = f2bf(a[1]); o[2] = f2bf(a[2]); o[3] = f2bf(a[3]);
    o[4] = f2bf(b[0]); o[5] = f2bf(b[1]); o[6] = f2bf(b[2]); o[7] = f2bf(b[3]);
    *(bf16x8*)(dst + i) = o;
  }
}

__global__ void bias_concat(const float* __restrict__ bq, const float* __restrict__ bk,
                            const float* __restrict__ bv, float* __restrict__ ball) {
  const int i = blockIdx.x * 256 + threadIdx.x;
  if (i < 3584) ball[i] = bq[i];
  else if (i < 4096) ball[i] = bk[i - 3584];
  else if (i < 4608) ball[i] = bv[i - 4096];
}

// ---------------- RoPE cos/sin table: [2048][64] ----------------
__global__ void rope_table(const int* __restrict__ pos, float* __restrict__ ctab,
                           float* __restrict__ stab) {
  const int s = blockIdx.x;
  const int i = threadIdx.x;  // 0..63
  const float p = (float)pos[s];
  // inv_freq = 1e6^(-i/64) = exp2(-i * log2(1e6)/64)
  const float ang = p * exp2f(-(float)i * 0.3114307588956902f);
  ctab[s * 64 + i] = cosf(ang);
  stab[s * 64 + i] = sinf(ang);
}

// In-place RoPE on q (heads 0..27) and k (heads 28..31) regions of qkv[2048][4608].
__global__ void __launch_bounds__(256) rope_apply(short* __restrict__ qkv,
                                                  const float* __restrict__ ctab,
                                                  const float* __restrict__ stab) {
  const int idx = blockIdx.x * 256 + threadIdx.x;  // 2048*32*8
  const int c = idx & 7;
  const int h = (idx >> 3) & 31;
  const int s = idx >> 8;
  short* base = qkv + (size_t)s * 4608 + h * 128 + c * 8;
  bf16x8 lo = *(bf16x8*)base;
  bf16x8 hi = *(bf16x8*)(base + 64);
  const float* cp = ctab + s * 64 + c * 8;
  const float* sp = stab + s * 64 + c * 8;
  bf16x8 lo2, hi2;
#pragma unroll
  for (int j = 0; j < 8; ++j) {
    const float x = bf2f(lo[j]), y = bf2f(hi[j]);
    const float cv = cp[j], sv = sp[j];
    lo2[j] = f2bf(x * cv - y * sv);
    hi2[j] = f2bf(y * cv + x * sv);
  }
  *(bf16x8*)base = lo2;
  *(bf16x8*)(base + 64) = hi2;
}

// V region of qkv -> V^T [4][128][2048]
__global__ void __launch_bounds__(256) v_transpose(const short* __restrict__ qkv,
                                                   short* __restrict__ vtb) {
  __shared__ short t[64 * 48];  // 64 s-rows x 32 d, stride 48 (16B-aligned rows)
  const int dt = blockIdx.x, st = blockIdx.y, kv = blockIdx.z;
  const int tid = threadIdx.x;
  {
    const int r = tid >> 2, c8 = tid & 3;
    const bf16x8 v = *(const bf16x8*)(qkv + (size_t)(st * 64 + r) * 4608 + 4096 +
                                      kv * 128 + dt * 32 + c8 * 8);
    *(bf16x8*)(t + r * 48 + c8 * 8) = v;
  }
  __syncthreads();
  {
    const int d = tid >> 3, c = tid & 7;
    bf16x8 v;
#pragma unroll
    for (int i = 0; i < 8; ++i) v[i] = t[(c * 8 + i) * 48 + d];
    *(bf16x8*)(vtb + ((size_t)kv * 128 + dt * 32 + d) * 2048 + st * 64 + c * 8) = v;
  }
}

// ---------------- bf16 GEMM: C[M,N] = A[M,K] * B[N,K]^T (+bias), m97-style ----
template <bool BIAS, bool OUTBF>
__global__ void __launch_bounds__(256) gemm_bt(const short* __restrict__ A,
                                               const short* __restrict__ B,
                                               const float* __restrict__ bias,
                                               void* __restrict__ outp,
                                               int M, int N, int K) {
  __shared__ short As[128 * 64];
  __shared__ short Bs[128 * 64];
  const int tid = threadIdx.x;
  const int lane = tid & 63, wave = tid >> 6;
  const int l15 = lane & 15, g = lane >> 4;
  const int wm = wave >> 1, wn = wave & 1;
  const int tm = blockIdx.y * 128, tn = blockIdx.x * 128;
  f32x4 acc[4][4] = {};
  const int ksteps = K >> 6;
  for (int ks = 0; ks < ksteps; ++ks) {
    __syncthreads();
    // stage A,B tiles [128][64]: 1024 x 16B chunks each; source pre-swizzled
    // (chunk-in-row ^ (row&7)) so swizzled ds_read_b128 below is 2-way (free).
#pragma unroll
    for (int it = 0; it < 4; ++it) {
      const int chunk = it * 256 + tid;
      const int row = chunk >> 3, sc8 = (chunk & 7) ^ (row & 7);
      gll16(A + (size_t)(tm + row) * K + ks * 64 + sc8 * 8,
            As + (it * 256 + wave * 64) * 8);
    }
#pragma unroll
    for (int it = 0; it < 4; ++it) {
      const int chunk = it * 256 + tid;
      const int row = chunk >> 3, sc8 = (chunk & 7) ^ (row & 7);
      gll16(B + (size_t)(tn + row) * K + ks * 64 + sc8 * 8,
            Bs + (it * 256 + wave * 64) * 8);
    }
    __syncthreads();
    bf16x8 af[4][2], bf[4][2];
#pragma unroll
    for (int m = 0; m < 4; ++m) {
      const int row = wm * 64 + m * 16 + l15;
#pragma unroll
      for (int kk = 0; kk < 2; ++kk) {
        const int c = (kk * 4 + g) ^ (row & 7);
        af[m][kk] = *(const bf16x8*)(As + row * 64 + c * 8);
      }
    }
#pragma unroll
    for (int n = 0; n < 4; ++n) {
      const int row = wn * 64 + n * 16 + l15;
#pragma unroll
      for (int kk = 0; kk < 2; ++kk) {
        const int c = (kk * 4 + g) ^ (row & 7);
        bf[n][kk] = *(const bf16x8*)(Bs + row * 64 + c * 8);
      }
    }
#pragma unroll
    for (int m = 0; m < 4; ++m)
#pragma unroll
      for (int n = 0; n < 4; ++n) {
        acc[m][n] = MFMA16(af[m][0], bf[n][0], acc[m][n]);
        acc[m][n] = MFMA16(af[m][1], bf[n][1], acc[m][n]);
      }
  }
  // epilogue: C/D layout col=lane&15, row=(lane>>4)*4+reg (guide §3, m89/m91)
#pragma unroll
  for (int m = 0; m < 4; ++m) {
    const int row0 = tm + wm * 64 + m * 16 + g * 4;
#pragma unroll
    for (int n = 0; n < 4; ++n) {
      const int col = tn + wn * 64 + n * 16 + l15;
      const float bv = BIAS ? bias[col] : 0.0f;
#pragma unroll
      for (int r = 0; r < 4; ++r) {
        const float v = acc[m][n][r] + bv;
        if (OUTBF)
          ((short*)outp)[(size_t)(row0 + r) * N + col] = f2bf(v);
        else
          ((float*)outp)[(size_t)(row0 + r) * N + col] = v;
      }
    }
  }
}

// ---------------- flash attention: 4 waves x 16 q-rows, KV tiles of 64 -------
__global__ void __launch_bounds__(256) attn_kernel(const short* __restrict__ qkv,
                                                   const short* __restrict__ vtb,
                                                   short* __restrict__ outb) {
  const int head = blockIdx.y;
  const int kvh = head / 7;  // GQA group = 28/4
  const int qb = ((int)gridDim.x - 1 - (int)blockIdx.x) * 64;  // longest first
  const int tid = threadIdx.x;
  const int lane = tid & 63, wave = tid >> 6;
  const int l15 = lane & 15, g = lane >> 4;
  __shared__ short Ks[64 * 128];   // K tile, src-swizzled
  __shared__ short Vs[128 * 64];   // V^T tile, src-swizzled
  __shared__ short Ps[4][16 * 64]; // per-wave P, swizzled

  bf16x8 qf[4];
  {
    const short* qptr = qkv + (size_t)(qb + wave * 16 + l15) * 4608 + head * 128 + g * 8;
#pragma unroll
    for (int ds = 0; ds < 4; ++ds) qf[ds] = *(const bf16x8*)(qptr + ds * 32);
  }
  f32x4 o[8] = {};
  float mrun[4] = {-__builtin_inff(), -__builtin_inff(), -__builtin_inff(), -__builtin_inff()};
  float lrun[4] = {0.f, 0.f, 0.f, 0.f};
  const short* kbase = qkv + 3584 + kvh * 128;
  const short* vbase = vtb + (size_t)kvh * 128 * 2048;
  const int ntiles = (qb >> 6) + 1;
  const float SCALE = 0.08838834764831845f;  // 128^-0.5

  for (int t = 0; t < ntiles; ++t) {
    const int kb = t * 64;
    __syncthreads();
#pragma unroll
    for (int it = 0; it < 4; ++it) {  // K tile: 64 rows x 16 chunks
      const int chunk = it * 256 + tid;
      const int row = chunk >> 4, sc = (chunk & 15) ^ (row & 7);
      gll16(kbase + (size_t)(kb + row) * 4608 + sc * 8, Ks + (it * 256 + wave * 64) * 8);
    }
#pragma unroll
    for (int it = 0; it < 4; ++it) {  // V^T tile: 128 rows x 8 chunks
      const int chunk = it * 256 + tid;
      const int row = chunk >> 3, sc = (chunk & 7) ^ (row & 7);
      gll16(vbase + (size_t)row * 2048 + kb + sc * 8, Vs + (it * 256 + wave * 64) * 8);
    }
    __syncthreads();

    // S = Q K^T  (C-layout: row=q=(g*4+r), col=key=l15+16n)
    f32x4 sf[4] = {};
#pragma unroll
    for (int n = 0; n < 4; ++n) {
      const int krow = n * 16 + l15;
#pragma unroll
      for (int ds = 0; ds < 4; ++ds) {
        const int c = (ds * 4 + g) ^ (krow & 7);
        const bf16x8 kf = *(const bf16x8*)(Ks + krow * 128 + c * 8);
        sf[n] = MFMA16(qf[ds], kf, sf[n]);
      }
    }
    const bool diag = (kb == qb);
    float alpha[4];
#pragma unroll
    for (int r = 0; r < 4; ++r) {
      const int qr = qb + wave * 16 + g * 4 + r;
#pragma unroll
      for (int n = 0; n < 4; ++n) {
        float v = sf[n][r] * SCALE;
        if (diag && (kb + n * 16 + l15) > qr) v = -__builtin_inff();
        sf[n][r] = v;
      }
      float mx = fmaxf(fmaxf(sf[0][r], sf[1][r]), fmaxf(sf[2][r], sf[3][r]));
      mx = fmaxf(mx, __shfl_xor(mx, 1));
      mx = fmaxf(mx, __shfl_xor(mx, 2));
      mx = fmaxf(mx, __shfl_xor(mx, 4));
      mx = fmaxf(mx, __shfl_xor(mx, 8));
      const float mnew = fmaxf(mrun[r], mx);
      alpha[r] = exp2f((mrun[r] - mnew) * LOG2E);
      mrun[r] = mnew;
    }
    float rs[4] = {0.f, 0.f, 0.f, 0.f};
#pragma unroll
    for (int n = 0; n < 4; ++n) {
#pragma unroll
      for (int r = 0; r < 4; ++r) {
        const float p = exp2f((sf[n][r] - mrun[r]) * LOG2E);
        rs[r] += p;
        const int prow = g * 4 + r, key = n * 16 + l15;
        const int cp = (key >> 3) ^ (prow & 7);
        Ps[wave][prow * 64 + cp * 8 + (key & 7)] = f2bf(p);
      }
    }
#pragma unroll
    for (int r = 0; r < 4; ++r) {
      float s = rs[r];
      s += __shfl_xor(s, 1);
      s += __shfl_xor(s, 2);
      s += __shfl_xor(s, 4);
      s += __shfl_xor(s, 8);
      lrun[r] = lrun[r] * alpha[r] + s;
#pragma unroll
      for (int nd = 0; nd < 8; ++nd) o[nd][r] *= alpha[r];
    }
    // O += P V   (A-frag from Ps, B-frag from V^T tile)
    bf16x8 pf[2];
#pragma unroll
    for (int ksl = 0; ksl < 2; ++ksl) {
      const int c = (ksl * 4 + g) ^ (l15 & 7);
      pf[ksl] = *(const bf16x8*)(&Ps[wave][l15 * 64 + c * 8]);
    }
#pragma unroll
    for (int nd = 0; nd < 8; ++nd) {
      const int vrow = nd * 16 + l15;
#pragma unroll
      for (int ksl = 0; ksl < 2; ++ksl) {
        const int c = (ksl * 4 + g) ^ (vrow & 7);
        const bf16x8 vf = *(const bf16x8*)(Vs + vrow * 64 + c * 8);
        o[nd] = MFMA16(pf[ksl], vf, o[nd]);
      }
    }
  }
#pragma unroll
  for (int r = 0; r < 4; ++r) lrun[r] = 1.0f / lrun[r];
#pragma unroll
  for (int nd = 0; nd < 8; ++nd) {
#pragma unroll
    for (int r = 0; r < 4; ++r) {
      const int qr = qb + wave * 16 + g * 4 + r;
      outb[(size_t)qr * 3584 + head * 128 + nd * 16 + l15] = f2bf(o[nd][r] * lrun[r]);
    }
  }
}

extern "C" void kernel_launch(void* const* d_in, const int* in_sizes, int n_in,
                              void* d_out, int out_size, void* d_ws, size_t ws_size,
                              hipStream_t stream) {
  const float* h  = (const float*)d_in[0];
  const int* pos  = (const int*)d_in[1];
  const float* Wq = (const float*)d_in[2];
  const float* bq = (const float*)d_in[3];
  const float* Wk = (const float*)d_in[4];
  const float* bk = (const float*)d_in[5];
  const float* Wv = (const float*)d_in[6];
  const float* bv = (const float*)d_in[7];
  const float* Wo = (const float*)d_in[8];
  float* out = (float*)d_out;

  char* w = (char*)d_ws;
  short* hbf  = (short*)w; w += (size_t)2048 * 3584 * 2;  // also reused as attn output
  short* Wall = (short*)w; w += (size_t)4608 * 3584 * 2;  // QKV weights, later reused for Wo
  float* ball = (float*)w; w += 4608 * 4;
  short* qkvp = (short*)w; w += (size_t)2048 * 4608 * 2;
  float* ctab = (float*)w; w += 2048 * 64 * 4;
  float* stab = (float*)w; w += 2048 * 64 * 4;
  short* vtb  = (short*)w; w += (size_t)4 * 128 * 2048 * 2;
  short* attnb = hbf;   // hbf dead after QKV GEMM
  short* Wob = Wall;    // Wall dead after QKV GEMM (33MB >= 25.7MB)

  cvt_kernel<<<2048, 256, 0, stream>>>(h, hbf, (long long)2048 * 3584);
  cvt_kernel<<<2048, 256, 0, stream>>>(Wq, Wall, (long long)3584 * 3584);
  cvt_kernel<<<512, 256, 0, stream>>>(Wk, Wall + (size_t)3584 * 3584, (long long)512 * 3584);
  cvt_kernel<<<512, 256, 0, stream>>>(Wv, Wall + (size_t)4096 * 3584, (long long)512 * 3584);
  bias_concat<<<18, 256, 0, stream>>>(bq, bk, bv, ball);
  rope_table<<<2048, 64, 0, stream>>>(pos, ctab, stab);

  gemm_bt<true, true><<<dim3(36, 16), 256, 0, stream>>>(hbf, Wall, ball, qkvp,
                                                        2048, 4608, 3584);
  rope_apply<<<2048, 256, 0, stream>>>(qkvp, ctab, stab);
  v_transpose<<<dim3(4, 32, 4), 256, 0, stream>>>(qkvp, vtb);
  cvt_kernel<<<2048, 256, 0, stream>>>(Wo, Wob, (long long)3584 * 3584);

  attn_kernel<<<dim3(32, 28), 256, 0, stream>>>(qkvp, vtb, attnb);

  gemm_bt<false, false><<<dim3(28, 16), 256, 0, stream>>>(attnb, Wob, nullptr, out,
                                                          2048, 3584, 3584);
}

// Round 2
// 283.087 us; speedup vs baseline: 1.3978x; 1.3978x over previous
//
#include <hip/hip_runtime.h>

typedef __attribute__((ext_vector_type(4))) float f32x4;
typedef __attribute__((ext_vector_type(8))) short bf16x8;

#define MFMA16(a, b, c) __builtin_amdgcn_mfma_f32_16x16x32_bf16((a), (b), (c), 0, 0, 0)
#define LOG2E 1.44269504088896340736f

static __device__ __forceinline__ float bf2f(short u) {
  unsigned x = ((unsigned)(unsigned short)u) << 16;
  return __builtin_bit_cast(float, x);
}
static __device__ __forceinline__ short f2bf(float f) {
  unsigned u = __builtin_bit_cast(unsigned, f);
  u += 0x7fffu + ((u >> 16) & 1u);
  return (short)(u >> 16);
}
// global -> LDS direct DMA, 16B per lane. LDS dest is wave-uniform base +
// lane*16 (guide §5); swizzle done on the GLOBAL source address (rule #21).
static __device__ __forceinline__ void gll16(const void* g, void* l) {
  __builtin_amdgcn_global_load_lds(
      (const __attribute__((address_space(1))) unsigned*)(unsigned long long)g,
      (__attribute__((address_space(3))) unsigned*)(unsigned)(unsigned long long)l,
      16, 0, 0);
}

// ---------------- f32 -> bf16 conversion (vectorized, G13) ----------------
__global__ void __launch_bounds__(256) cvt_kernel(const float* __restrict__ src,
                                                  short* __restrict__ dst,
                                                  long long n) {
  long long i = ((long long)blockIdx.x * 256 + threadIdx.x) * 8;
  const long long stride = (long long)gridDim.x * 256 * 8;
  for (; i < n; i += stride) {
    f32x4 a = *(const f32x4*)(src + i);
    f32x4 b = *(const f32x4*)(src + i + 4);
    bf16x8 o;
    o[0] = f2bf(a[0]); o[1] = f2bf(a[1]); o[2] = f2bf(a[2]); o[3] = f2bf(a[3]);
    o[4] = f2bf(b[0]); o[5] = f2bf(b[1]); o[6] = f2bf(b[2]); o[7] = f2bf(b[3]);
    *(bf16x8*)(dst + i) = o;
  }
}

__global__ void bias_concat(const float* __restrict__ bq, const float* __restrict__ bk,
                            const float* __restrict__ bv, float* __restrict__ ball) {
  const int i = blockIdx.x * 256 + threadIdx.x;
  if (i < 3584) ball[i] = bq[i];
  else if (i < 4096) ball[i] = bk[i - 3584];
  else if (i < 4608) ball[i] = bv[i - 4096];
}

// ---------------- RoPE cos/sin table: [2048][64] ----------------
__global__ void rope_table(const int* __restrict__ pos, float* __restrict__ ctab,
                           float* __restrict__ stab) {
  const int s = blockIdx.x;
  const int i = threadIdx.x;  // 0..63
  const float p = (float)pos[s];
  const float ang = p * exp2f(-(float)i * 0.3114307588956902f);
  ctab[s * 64 + i] = cosf(ang);
  stab[s * 64 + i] = sinf(ang);
}

// In-place RoPE on q/k regions of qkv[2048][4608]. Q heads (h<28) are
// pre-scaled by SCALE*LOG2E so attention scores come out in exp2-domain.
__global__ void __launch_bounds__(256) rope_apply(short* __restrict__ qkv,
                                                  const float* __restrict__ ctab,
                                                  const float* __restrict__ stab) {
  const int idx = blockIdx.x * 256 + threadIdx.x;  // 2048*32*8
  const int c = idx & 7;
  const int h = (idx >> 3) & 31;
  const int s = idx >> 8;
  const float qs = (h < 28) ? (0.08838834764831845f * LOG2E) : 1.0f;
  short* base = qkv + (size_t)s * 4608 + h * 128 + c * 8;
  bf16x8 lo = *(bf16x8*)base;
  bf16x8 hi = *(bf16x8*)(base + 64);
  const float* cp = ctab + s * 64 + c * 8;
  const float* sp = stab + s * 64 + c * 8;
  bf16x8 lo2, hi2;
#pragma unroll
  for (int j = 0; j < 8; ++j) {
    const float x = bf2f(lo[j]), y = bf2f(hi[j]);
    const float cv = cp[j], sv = sp[j];
    lo2[j] = f2bf((x * cv - y * sv) * qs);
    hi2[j] = f2bf((y * cv + x * sv) * qs);
  }
  *(bf16x8*)base = lo2;
  *(bf16x8*)(base + 64) = hi2;
}

// V region of qkv -> V^T [4][128][2048]
__global__ void __launch_bounds__(256) v_transpose(const short* __restrict__ qkv,
                                                   short* __restrict__ vtb) {
  __shared__ short t[64 * 48];
  const int dt = blockIdx.x, st = blockIdx.y, kv = blockIdx.z;
  const int tid = threadIdx.x;
  {
    const int r = tid >> 2, c8 = tid & 3;
    const bf16x8 v = *(const bf16x8*)(qkv + (size_t)(st * 64 + r) * 4608 + 4096 +
                                      kv * 128 + dt * 32 + c8 * 8);
    *(bf16x8*)(t + r * 48 + c8 * 8) = v;
  }
  __syncthreads();
  {
    const int d = tid >> 3, c = tid & 7;
    bf16x8 v;
#pragma unroll
    for (int i = 0; i < 8; ++i) v[i] = t[(c * 8 + i) * 48 + d];
    *(bf16x8*)(vtb + ((size_t)kv * 128 + dt * 32 + d) * 2048 + st * 64 + c * 8) = v;
  }
}

// ---------------- bf16 GEMM: C[M,N] = A[M,K] * B[N,K]^T (+bias), m97-style ----
template <bool BIAS, bool OUTBF>
__global__ void __launch_bounds__(256) gemm_bt(const short* __restrict__ A,
                                               const short* __restrict__ B,
                                               const float* __restrict__ bias,
                                               void* __restrict__ outp,
                                               int M, int N, int K) {
  __shared__ short As[128 * 64];
  __shared__ short Bs[128 * 64];
  const int tid = threadIdx.x;
  const int lane = tid & 63, wave = tid >> 6;
  const int l15 = lane & 15, g = lane >> 4;
  const int wm = wave >> 1, wn = wave & 1;
  const int tm = blockIdx.y * 128, tn = blockIdx.x * 128;
  f32x4 acc[4][4] = {};
  const int ksteps = K >> 6;
  for (int ks = 0; ks < ksteps; ++ks) {
    __syncthreads();
#pragma unroll
    for (int it = 0; it < 4; ++it) {
      const int chunk = it * 256 + tid;
      const int row = chunk >> 3, sc8 = (chunk & 7) ^ (row & 7);
      gll16(A + (size_t)(tm + row) * K + ks * 64 + sc8 * 8,
            As + (it * 256 + wave * 64) * 8);
    }
#pragma unroll
    for (int it = 0; it < 4; ++it) {
      const int chunk = it * 256 + tid;
      const int row = chunk >> 3, sc8 = (chunk & 7) ^ (row & 7);
      gll16(B + (size_t)(tn + row) * K + ks * 64 + sc8 * 8,
            Bs + (it * 256 + wave * 64) * 8);
    }
    __syncthreads();
    bf16x8 af[4][2], bf[4][2];
#pragma unroll
    for (int m = 0; m < 4; ++m) {
      const int row = wm * 64 + m * 16 + l15;
#pragma unroll
      for (int kk = 0; kk < 2; ++kk) {
        const int c = (kk * 4 + g) ^ (row & 7);
        af[m][kk] = *(const bf16x8*)(As + row * 64 + c * 8);
      }
    }
#pragma unroll
    for (int n = 0; n < 4; ++n) {
      const int row = wn * 64 + n * 16 + l15;
#pragma unroll
      for (int kk = 0; kk < 2; ++kk) {
        const int c = (kk * 4 + g) ^ (row & 7);
        bf[n][kk] = *(const bf16x8*)(Bs + row * 64 + c * 8);
      }
    }
#pragma unroll
    for (int m = 0; m < 4; ++m)
#pragma unroll
      for (int n = 0; n < 4; ++n) {
        acc[m][n] = MFMA16(af[m][0], bf[n][0], acc[m][n]);
        acc[m][n] = MFMA16(af[m][1], bf[n][1], acc[m][n]);
      }
  }
#pragma unroll
  for (int m = 0; m < 4; ++m) {
    const int row0 = tm + wm * 64 + m * 16 + g * 4;
#pragma unroll
    for (int n = 0; n < 4; ++n) {
      const int col = tn + wn * 64 + n * 16 + l15;
      const float bv = BIAS ? bias[col] : 0.0f;
#pragma unroll
      for (int r = 0; r < 4; ++r) {
        const float v = acc[m][n][r] + bv;
        if (OUTBF)
          ((short*)outp)[(size_t)(row0 + r) * N + col] = f2bf(v);
        else
          ((float*)outp)[(size_t)(row0 + r) * N + col] = v;
      }
    }
  }
}

// ---------------- flash attention, 2-phase pipelined, paired q-tiles --------
// grid (16,28): 448 uniform blocks, each = q-tiles {i, 31-i} = 33 kv-tile-iters.
// Block remap: kv-head group g gets lids with lid%8 in {2g,2g+1} -> each
// XCD's L2 caches ONE kv-head's K/V (1 MB).
__global__ void __launch_bounds__(256) attn_kernel(const short* __restrict__ qkv,
                                                   const short* __restrict__ vtb,
                                                   short* __restrict__ outb) {
  const int lid = (int)blockIdx.x + ((int)blockIdx.y << 4);
  const int kvh = (lid & 7) >> 1;
  const int u = ((lid >> 3) << 1) + (lid & 1);  // 0..111 within kv group
  const int head = kvh * 7 + (u >> 4);
  const int qtA = u & 15, qtB = 31 - qtA;

  const int tid = threadIdx.x;
  const int lane = tid & 63, wave = tid >> 6;
  const int l15 = lane & 15, g = lane >> 4;

  __shared__ short Ks[2][64 * 128];
  __shared__ short Vs[2][128 * 64];
  __shared__ short Ps[4][16 * 64];

  const short* kbase = qkv + 3584 + kvh * 128;
  const short* vbase = vtb + (size_t)kvh * 128 * 2048;
  const float NINF = -__builtin_inff();

  bf16x8 qf[4];
  f32x4 o[8];
  float mrun[4], lrun[4];

  // --- load Q fragments for q-tile qt ---
#define LOADQ(qt)                                                                  \
  {                                                                                \
    const short* qptr =                                                            \
        qkv + (size_t)((qt)*64 + wave * 16 + l15) * 4608 + head * 128 + g * 8;     \
    _Pragma("unroll") for (int ds = 0; ds < 4; ++ds) qf[ds] =                      \
        *(const bf16x8*)(qptr + ds * 32);                                          \
  }
#define RESET()                                                                    \
  {                                                                                \
    _Pragma("unroll") for (int nd = 0; nd < 8; ++nd) o[nd] = f32x4{0.f,0.f,0.f,0.f}; \
    _Pragma("unroll") for (int r = 0; r < 4; ++r) { mrun[r] = NINF; lrun[r] = 0.f; } \
  }
  // --- stage K/V tile kv into buffer b (src-swizzled for ds_read_b128) ---
#define STAGE(kv, b)                                                               \
  {                                                                                \
    _Pragma("unroll") for (int it = 0; it < 4; ++it) {                             \
      const int chunk = it * 256 + tid;                                            \
      const int row = chunk >> 4, sc = (chunk & 15) ^ (row & 7);                   \
      gll16(kbase + (size_t)((kv)*64 + row) * 4608 + sc * 8,                       \
            &Ks[b][(it * 256 + wave * 64) * 8]);                                   \
    }                                                                              \
    _Pragma("unroll") for (int it = 0; it < 4; ++it) {                             \
      const int chunk = it * 256 + tid;                                            \
      const int row = chunk >> 3, sc = (chunk & 7) ^ (row & 7);                    \
      gll16(vbase + (size_t)row * 2048 + (kv)*64 + sc * 8,                         \
            &Vs[b][(it * 256 + wave * 64) * 8]);                                   \
    }                                                                              \
  }

  RESET();
  LOADQ(qtA);
  STAGE(0, 0);
  __syncthreads();
  int cur = 0;

  for (int s = 0; s < 33; ++s) {
    if (s < 32) {
      const int sn = s + 1;
      const int kvn = (sn <= qtA) ? sn : sn - qtA - 1;
      STAGE(kvn, cur ^ 1);
    }
    const int qt = (s <= qtA) ? qtA : qtB;
    const int kv = (s <= qtA) ? s : s - qtA - 1;
    const bool diag = (s == qtA) || (s == 32);

    // S = Q K^T (exp2-domain: Q pre-scaled by SCALE*LOG2E)
    f32x4 sf[4] = {};
    __builtin_amdgcn_s_setprio(1);
#pragma unroll
    for (int n = 0; n < 4; ++n) {
      const int krow = n * 16 + l15;
#pragma unroll
      for (int ds = 0; ds < 4; ++ds) {
        const int c = (ds * 4 + g) ^ (krow & 7);
        const bf16x8 kf = *(const bf16x8*)(&Ks[cur][krow * 128 + c * 8]);
        sf[n] = MFMA16(qf[ds], kf, sf[n]);
      }
    }
    __builtin_amdgcn_s_setprio(0);

    if (diag) {
#pragma unroll
      for (int r = 0; r < 4; ++r) {
        const int qr = qt * 64 + wave * 16 + g * 4 + r;
#pragma unroll
        for (int n = 0; n < 4; ++n)
          if (kv * 64 + n * 16 + l15 > qr) sf[n][r] = NINF;
      }
    }
    // defer-max (T13): per-lane partial max is enough to CHECK the bound
    float pmax[4];
#pragma unroll
    for (int r = 0; r < 4; ++r)
      pmax[r] = fmaxf(fmaxf(sf[0][r], sf[1][r]), fmaxf(sf[2][r], sf[3][r]));
    const bool need = (pmax[0] > mrun[0] + 8.f) || (pmax[1] > mrun[1] + 8.f) ||
                      (pmax[2] > mrun[2] + 8.f) || (pmax[3] > mrun[3] + 8.f);
    if (__any(need)) {
#pragma unroll
      for (int r = 0; r < 4; ++r) {
        float mx = pmax[r];
        mx = fmaxf(mx, __shfl_xor(mx, 1));
        mx = fmaxf(mx, __shfl_xor(mx, 2));
        mx = fmaxf(mx, __shfl_xor(mx, 4));
        mx = fmaxf(mx, __shfl_xor(mx, 8));
        const float mnew = fmaxf(mrun[r], mx);
        const float alpha = exp2f(mrun[r] - mnew);
        mrun[r] = mnew;
        lrun[r] *= alpha;
#pragma unroll
        for (int nd = 0; nd < 8; ++nd) o[nd][r] *= alpha;
      }
    }
    // P = exp2(S - m); per-lane partial row-sums (reduced once at finalize)
#pragma unroll
    for (int n = 0; n < 4; ++n) {
#pragma unroll
      for (int r = 0; r < 4; ++r) {
        const float p = exp2f(sf[n][r] - mrun[r]);
        lrun[r] += p;
        const int prow = g * 4 + r, key = n * 16 + l15;
        const int cp = (key >> 3) ^ (prow & 7);
        Ps[wave][prow * 64 + cp * 8 + (key & 7)] = f2bf(p);
      }
    }
    // O += P V
    bf16x8 pf[2];
#pragma unroll
    for (int ksl = 0; ksl < 2; ++ksl) {
      const int c = (ksl * 4 + g) ^ (l15 & 7);
      pf[ksl] = *(const bf16x8*)(&Ps[wave][l15 * 64 + c * 8]);
    }
    __builtin_amdgcn_s_setprio(1);
#pragma unroll
    for (int nd = 0; nd < 8; ++nd) {
      const int vrow = nd * 16 + l15;
#pragma unroll
      for (int ksl = 0; ksl < 2; ++ksl) {
        const int c = (ksl * 4 + g) ^ (vrow & 7);
        const bf16x8 vf = *(const bf16x8*)(&Vs[cur][vrow * 64 + c * 8]);
        o[nd] = MFMA16(pf[ksl], vf, o[nd]);
      }
    }
    __builtin_amdgcn_s_setprio(0);

    if (diag) {  // end of a q-tile context: reduce lrun, write O
      float inv[4];
#pragma unroll
      for (int r = 0; r < 4; ++r) {
        float sum = lrun[r];
        sum += __shfl_xor(sum, 1);
        sum += __shfl_xor(sum, 2);
        sum += __shfl_xor(sum, 4);
        sum += __shfl_xor(sum, 8);
        inv[r] = 1.0f / sum;
      }
#pragma unroll
      for (int nd = 0; nd < 8; ++nd) {
#pragma unroll
        for (int r = 0; r < 4; ++r) {
          const int qr = qt * 64 + wave * 16 + g * 4 + r;
          outb[(size_t)qr * 3584 + head * 128 + nd * 16 + l15] = f2bf(o[nd][r] * inv[r]);
        }
      }
      if (s == qtA) {  // switch to context B
        RESET();
        LOADQ(qtB);
      }
    }
    __syncthreads();
    cur ^= 1;
  }
#undef LOADQ
#undef RESET
#undef STAGE
}

extern "C" void kernel_launch(void* const* d_in, const int* in_sizes, int n_in,
                              void* d_out, int out_size, void* d_ws, size_t ws_size,
                              hipStream_t stream) {
  const float* h  = (const float*)d_in[0];
  const int* pos  = (const int*)d_in[1];
  const float* Wq = (const float*)d_in[2];
  const float* bq = (const float*)d_in[3];
  const float* Wk = (const float*)d_in[4];
  const float* bk = (const float*)d_in[5];
  const float* Wv = (const float*)d_in[6];
  const float* bv = (const float*)d_in[7];
  const float* Wo = (const float*)d_in[8];
  float* out = (float*)d_out;

  char* w = (char*)d_ws;
  short* hbf  = (short*)w; w += (size_t)2048 * 3584 * 2;
  short* Wall = (short*)w; w += (size_t)4608 * 3584 * 2;
  float* ball = (float*)w; w += 4608 * 4;
  short* qkvp = (short*)w; w += (size_t)2048 * 4608 * 2;
  float* ctab = (float*)w; w += 2048 * 64 * 4;
  float* stab = (float*)w; w += 2048 * 64 * 4;
  short* vtb  = (short*)w; w += (size_t)4 * 128 * 2048 * 2;
  short* attnb = hbf;
  short* Wob = Wall;

  cvt_kernel<<<2048, 256, 0, stream>>>(h, hbf, (long long)2048 * 3584);
  cvt_kernel<<<2048, 256, 0, stream>>>(Wq, Wall, (long long)3584 * 3584);
  cvt_kernel<<<512, 256, 0, stream>>>(Wk, Wall + (size_t)3584 * 3584, (long long)512 * 3584);
  cvt_kernel<<<512, 256, 0, stream>>>(Wv, Wall + (size_t)4096 * 3584, (long long)512 * 3584);
  bias_concat<<<18, 256, 0, stream>>>(bq, bk, bv, ball);
  rope_table<<<2048, 64, 0, stream>>>(pos, ctab, stab);

  gemm_bt<true, true><<<dim3(36, 16), 256, 0, stream>>>(hbf, Wall, ball, qkvp,
                                                        2048, 4608, 3584);
  rope_apply<<<2048, 256, 0, stream>>>(qkvp, ctab, stab);
  v_transpose<<<dim3(4, 32, 4), 256, 0, stream>>>(qkvp, vtb);
  cvt_kernel<<<2048, 256, 0, stream>>>(Wo, Wob, (long long)3584 * 3584);

  attn_kernel<<<dim3(16, 28), 256, 0, stream>>>(qkvp, vtb, attnb);

  gemm_bt<false, false><<<dim3(28, 16), 256, 0, stream>>>(attnb, Wob, nullptr, out,
                                                          2048, 3584, 3584);
}